// Round 1
// baseline (352.989 us; speedup 1.0000x reference)
//
#include <hip/hip_runtime.h>

#define D 64
#define NK 1024
#define BQ 128        // queries per block
#define KT 128        // codes per LDS tile
#define NTILE (NK / KT)
#define QTOTAL 65536
#define NELEM (QTOTAL * D)      // 4194304
#define LOSS_OFF 4194304
#define IDX_OFF  4194305

// Kernel 1: |e_k|^2 for all codes into workspace; also zero the loss slot in d_out.
__global__ __launch_bounds__(256) void vq_e2_kernel(const float* __restrict__ emb,
                                                    float* __restrict__ e2,
                                                    float* __restrict__ out) {
    int k = blockIdx.x * blockDim.x + threadIdx.x;
    if (k == 0) out[LOSS_OFF] = 0.0f;
    if (k < NK) {
        const float4* e4 = (const float4*)(emb + k * D);
        float s = 0.f;
#pragma unroll
        for (int i = 0; i < D / 4; ++i) {
            float4 v = e4[i];
            s += v.x * v.x + v.y * v.y + v.z * v.z + v.w * v.w;
        }
        e2[k] = s;
    }
}

// Main kernel: one query per thread-pair. tid<128 covers lower 64 codes of each
// tile, tid>=128 covers upper 64. x lives in 64 VGPRs; codebook tile in LDS,
// read at wave-uniform addresses (broadcast, no bank conflicts).
__global__ __launch_bounds__(256, 2) void vq_main_kernel(const float* __restrict__ x,
                                                         const float* __restrict__ emb,
                                                         const float* __restrict__ e2g,
                                                         float* __restrict__ out) {
    __shared__ float4 es4[KT * D / 4];   // 32 KiB code tile
    __shared__ float  e2s[KT];
    __shared__ float  ms[256];
    __shared__ int    mi[256];

    const int tid  = threadIdx.x;
    const int half = tid >> 7;       // 0 or 1
    const int ql   = tid & 127;
    const int q    = blockIdx.x * BQ + ql;

    // Load this thread's query vector into registers (16 x float4 = 64 VGPRs).
    float4 xv[D / 4];
    const float4* xp = (const float4*)(x + (long)q * D);
#pragma unroll
    for (int i = 0; i < D / 4; ++i) xv[i] = xp[i];

    float best_s = 3.4e38f;
    int   best_c = 0;

    const float* es = (const float*)es4;

    for (int t = 0; t < NTILE; ++t) {
        // Stage 128-code tile: 2048 float4, 256 threads -> 8 each, coalesced.
        const float4* src = (const float4*)emb + t * (KT * D / 4);
#pragma unroll
        for (int j = 0; j < (KT * D / 4) / 256; ++j)
            es4[tid + 256 * j] = src[tid + 256 * j];
        if (tid < KT) e2s[tid] = e2g[t * KT + tid];
        __syncthreads();

        const int cbase = half * (KT / 2);
#pragma unroll 2
        for (int c = 0; c < KT / 2; ++c) {
            const int cc = cbase + c;
            const float4* ep = (const float4*)(es + cc * D);
            float4 a = {0.f, 0.f, 0.f, 0.f};   // 4 independent FMA chains
#pragma unroll
            for (int i = 0; i < D / 4; ++i) {
                float4 e = ep[i];
                a.x = fmaf(xv[i].x, e.x, a.x);
                a.y = fmaf(xv[i].y, e.y, a.y);
                a.z = fmaf(xv[i].z, e.z, a.z);
                a.w = fmaf(xv[i].w, e.w, a.w);
            }
            float dot = (a.x + a.y) + (a.z + a.w);
            float s = 0.5f * e2s[cc] - dot;    // argmin-equivalent to |x-e|^2
            int idx = t * KT + cc;
            if (s < best_s) { best_s = s; best_c = idx; }
        }
        __syncthreads();
    }

    ms[tid] = best_s;
    mi[tid] = best_c;
    __syncthreads();

    if (tid < BQ) {
        // Merge the two halves (strict < : ties keep half-0; exact fp ties on
        // random normal data are measure-zero).
        float s1 = ms[tid + 128];
        int   i1 = mi[tid + 128];
        if (s1 < best_s) { best_s = s1; best_c = i1; }

        // encoding index (written as float; out buffer is read as f32)
        out[IDX_OFF + q] = (float)best_c;

        // gather quantized row + per-query loss contribution
        const float4* eb = (const float4*)(emb + best_c * D);
        float4* o4 = (float4*)(out + (long)q * D);
        float lsum = 0.f;
#pragma unroll
        for (int i = 0; i < D / 4; ++i) {
            float4 e = eb[i];
            o4[i] = e;
            float dx = e.x - xv[i].x;
            float dy = e.y - xv[i].y;
            float dz = e.z - xv[i].z;
            float dw = e.w - xv[i].w;
            lsum += dx * dx + dy * dy + dz * dz + dw * dw;
        }
        // waves 0 and 1 are fully active here (tid<128) -> full 64-lane reduce
#pragma unroll
        for (int off = 32; off > 0; off >>= 1)
            lsum += __shfl_down(lsum, off, 64);
        if ((tid & 63) == 0)
            atomicAdd(&out[LOSS_OFF], lsum * (0.25f / (float)NELEM));
    }
}

extern "C" void kernel_launch(void* const* d_in, const int* in_sizes, int n_in,
                              void* d_out, int out_size, void* d_ws, size_t ws_size,
                              hipStream_t stream) {
    const float* inputs = (const float*)d_in[0];      // [65536, 64]
    const float* emb    = (const float*)d_in[1];      // [1024, 64]
    float* out = (float*)d_out;
    float* e2  = (float*)d_ws;                        // 1024 floats

    vq_e2_kernel<<<4, 256, 0, stream>>>(emb, e2, out);
    vq_main_kernel<<<QTOTAL / BQ, 256, 0, stream>>>(inputs, emb, e2, out);
}

// Round 3
// 203.229 us; speedup vs baseline: 1.7369x; 1.7369x over previous
//
#include <hip/hip_runtime.h>

#define D 64
#define NK 1024
#define QTOTAL 65536
#define NELEM (QTOTAL * D)      // 4194304
#define LOSS_OFF 4194304
#define IDX_OFF  4194305

typedef float f32x16 __attribute__((ext_vector_type(16)));

// Kernel 1: |e_k|^2 into workspace; zero the loss slot.
__global__ __launch_bounds__(256) void vq_e2_kernel(const float* __restrict__ emb,
                                                    float* __restrict__ e2,
                                                    float* __restrict__ out) {
    int k = blockIdx.x * blockDim.x + threadIdx.x;
    if (k == 0) out[LOSS_OFF] = 0.0f;
    if (k < NK) {
        const float4* e4 = (const float4*)(emb + k * D);
        float s = 0.f;
#pragma unroll
        for (int i = 0; i < D / 4; ++i) {
            float4 v = e4[i];
            s += v.x * v.x + v.y * v.y + v.z * v.z + v.w * v.w;
        }
        e2[k] = s;
    }
}

// 16 consecutive code elements (SGPR-resident, wave-uniform) against both
// queries; 4 independent FMA chains per query (chain j takes dims ≡ j mod 4,
// matching R1's accumulation order exactly).
#define DO_CHUNK(B, K) \
    aA0 = fmaf(B[0],  xA[4*K+0].x, aA0); aA1 = fmaf(B[1],  xA[4*K+0].y, aA1); \
    aA2 = fmaf(B[2],  xA[4*K+0].z, aA2); aA3 = fmaf(B[3],  xA[4*K+0].w, aA3); \
    aA0 = fmaf(B[4],  xA[4*K+1].x, aA0); aA1 = fmaf(B[5],  xA[4*K+1].y, aA1); \
    aA2 = fmaf(B[6],  xA[4*K+1].z, aA2); aA3 = fmaf(B[7],  xA[4*K+1].w, aA3); \
    aA0 = fmaf(B[8],  xA[4*K+2].x, aA0); aA1 = fmaf(B[9],  xA[4*K+2].y, aA1); \
    aA2 = fmaf(B[10], xA[4*K+2].z, aA2); aA3 = fmaf(B[11], xA[4*K+2].w, aA3); \
    aA0 = fmaf(B[12], xA[4*K+3].x, aA0); aA1 = fmaf(B[13], xA[4*K+3].y, aA1); \
    aA2 = fmaf(B[14], xA[4*K+3].z, aA2); aA3 = fmaf(B[15], xA[4*K+3].w, aA3); \
    aB0 = fmaf(B[0],  xB[4*K+0].x, aB0); aB1 = fmaf(B[1],  xB[4*K+0].y, aB1); \
    aB2 = fmaf(B[2],  xB[4*K+0].z, aB2); aB3 = fmaf(B[3],  xB[4*K+0].w, aB3); \
    aB0 = fmaf(B[4],  xB[4*K+1].x, aB0); aB1 = fmaf(B[5],  xB[4*K+1].y, aB1); \
    aB2 = fmaf(B[6],  xB[4*K+1].z, aB2); aB3 = fmaf(B[7],  xB[4*K+1].w, aB3); \
    aB0 = fmaf(B[8],  xB[4*K+2].x, aB0); aB1 = fmaf(B[9],  xB[4*K+2].y, aB1); \
    aB2 = fmaf(B[10], xB[4*K+2].z, aB2); aB3 = fmaf(B[11], xB[4*K+2].w, aB3); \
    aB0 = fmaf(B[12], xB[4*K+3].x, aB0); aB1 = fmaf(B[13], xB[4*K+3].y, aB1); \
    aB2 = fmaf(B[14], xB[4*K+3].z, aB2); aB3 = fmaf(B[15], xB[4*K+3].w, aB3);

// 512 blocks x 256 threads. Block owns 128 queries; each of the 4 waves owns a
// wave-uniform quarter of the codebook, streamed through SGPRs via SMEM
// (s_load_dwordx16): one v_fmac SGPR operand is free -> zero LDS/VMEM traffic
// in the hot loop. Each asm block is SELF-CONTAINED (loads + waitcnt together):
// no in-flight SGPRs ever cross an asm boundary, so compiler-inserted copies
// are always of completed values (R2's corruption is structurally impossible).
__global__ __launch_bounds__(256, 2) void vq_main_kernel(const float* __restrict__ x,
                                                         const float* __restrict__ emb,
                                                         const float* __restrict__ e2g,
                                                         float* __restrict__ out) {
    __shared__ float e2l[NK];        // 4 KB, broadcast-read (wave-uniform addr)
    __shared__ float sm_s[512];
    __shared__ int   sm_c[512];

    const int tid = threadIdx.x;
    const int l   = tid & 63;
    const int w   = tid >> 6;
    const int qbase = blockIdx.x * 128;
    const int qA = qbase + l;
    const int qB = qbase + 64 + l;

    // Stage e2 through the (coherent) vector path into LDS: 256 x float4.
    ((float4*)e2l)[tid] = ((const float4*)e2g)[tid];

    // Both queries resident in VGPRs (128 VGPRs).
    float4 xA[16], xB[16];
    const float4* xpA = (const float4*)(x + (long)qA * D);
    const float4* xpB = (const float4*)(x + (long)qB * D);
#pragma unroll
    for (int i = 0; i < 16; ++i) { xA[i] = xpA[i]; xB[i] = xpB[i]; }
    __syncthreads();

    const int code0 = __builtin_amdgcn_readfirstlane(w << 8);  // wave's first code
    const float* ep0 = emb + (long)code0 * D;

    float bestA = 3.4e38f, bestB = 3.4e38f;
    int idxA = 0, idxB = 0;

#pragma unroll 1
    for (int g = 0; g < 256; ++g) {
        const float* ep = ep0 + g * D;   // wave-uniform -> SGPR pair
        f32x16 b0, b1, b2, b3;
        asm volatile(
            "s_load_dwordx16 %0, %4, 0x0\n\t"
            "s_load_dwordx16 %1, %4, 0x40\n\t"
            "s_load_dwordx16 %2, %4, 0x80\n\t"
            "s_load_dwordx16 %3, %4, 0xC0\n\t"
            "s_waitcnt lgkmcnt(0)"
            : "=s"(b0), "=s"(b1), "=s"(b2), "=s"(b3)
            : "s"(ep));

        float aA0 = 0.f, aA1 = 0.f, aA2 = 0.f, aA3 = 0.f;
        float aB0 = 0.f, aB1 = 0.f, aB2 = 0.f, aB3 = 0.f;
        DO_CHUNK(b0, 0)
        DO_CHUNK(b1, 1)
        DO_CHUNK(b2, 2)
        DO_CHUNK(b3, 3)

        float dotA = (aA0 + aA1) + (aA2 + aA3);
        float dotB = (aB0 + aB1) + (aB2 + aB3);
        float e2c = e2l[code0 + g];           // uniform ds_read_b32: broadcast
        float sA = 0.5f * e2c - dotA;         // same math as passing R1
        float sB = 0.5f * e2c - dotB;
        int code = code0 + g;
        bool ltA = sA < bestA; bestA = ltA ? sA : bestA; idxA = ltA ? code : idxA;
        bool ltB = sB < bestB; bestB = ltB ? sB : bestB; idxB = ltB ? code : idxB;
    }

    // Cross-wave merge: ascending wave == ascending code range, strict < keeps
    // the first minimum (numpy argmin tie-break preserved).
    sm_s[w * 128 + l]      = bestA;  sm_c[w * 128 + l]      = idxA;
    sm_s[w * 128 + 64 + l] = bestB;  sm_c[w * 128 + 64 + l] = idxB;
    __syncthreads();

    if (tid < 128) {
        float bs = sm_s[tid];
        int   bc = sm_c[tid];
#pragma unroll
        for (int wv = 1; wv < 4; ++wv) {
            float s = sm_s[wv * 128 + tid];
            int   c = sm_c[wv * 128 + tid];
            if (s < bs) { bs = s; bc = c; }
        }
        const int q = qbase + tid;
        out[IDX_OFF + q] = (float)bc;

        const float4* eb = (const float4*)(emb + (long)bc * D);
        const float4* xq = (const float4*)(x + (long)q * D);
        float4* oq = (float4*)(out + (long)q * D);
        float lsum = 0.f;
#pragma unroll
        for (int i = 0; i < 16; ++i) {
            float4 e = eb[i];
            float4 xx = xq[i];
            oq[i] = e;
            float dx = e.x - xx.x, dy = e.y - xx.y, dz = e.z - xx.z, dw = e.w - xx.w;
            lsum += dx * dx + dy * dy + dz * dz + dw * dw;
        }
#pragma unroll
        for (int o = 32; o > 0; o >>= 1)
            lsum += __shfl_down(lsum, o, 64);
        if ((tid & 63) == 0)
            atomicAdd(&out[LOSS_OFF], lsum * (0.25f / (float)NELEM));
    }
}

extern "C" void kernel_launch(void* const* d_in, const int* in_sizes, int n_in,
                              void* d_out, int out_size, void* d_ws, size_t ws_size,
                              hipStream_t stream) {
    const float* inputs = (const float*)d_in[0];      // [65536, 64]
    const float* emb    = (const float*)d_in[1];      // [1024, 64]
    float* out = (float*)d_out;
    float* e2  = (float*)d_ws;                        // 1024 floats

    vq_e2_kernel<<<4, 256, 0, stream>>>(emb, e2, out);
    vq_main_kernel<<<QTOTAL / 128, 256, 0, stream>>>(inputs, emb, e2, out);
}